// Round 8
// baseline (1369.273 us; speedup 1.0000x reference)
//
#include <hip/hip_runtime.h>
#include <hip/hip_fp16.h>
#include <math.h>

// TransformerConvNet: 2x TransformerConv(heads=1) + ELU + MLP head + log_softmax
// N=100000 nodes, E=1600000 edges, F_IN=64, C1=32, C2=64, H1=128, NC=10
//
// R8: dense linears rewritten row-per-thread — x rows in registers (fp16),
// weights in LDS as fp16 read via wave-uniform b128 broadcast, v_dot2_f32_f16
// inner product. Kills the strided-scalar-LDS + redundant-global-x latency
// bind that made linear4 140 us.

#define SCAN_NB 256

typedef _Float16 h2 __attribute__((ext_vector_type(2)));
typedef _Float16 h8 __attribute__((ext_vector_type(8)));

__device__ __forceinline__ float dot2(h2 a, h2 b, float c) {
#if __has_builtin(__builtin_amdgcn_fdot2)
    return __builtin_amdgcn_fdot2(a, b, c, false);
#else
    return fmaf((float)a[0], (float)b[0], fmaf((float)a[1], (float)b[1], c));
#endif
}

// ---------- CSR build ----------
__global__ __launch_bounds__(256)
void count_rank_kernel(const int* __restrict__ dst, int* __restrict__ deg,
                       int* __restrict__ rank, int e) {
    for (int i = blockIdx.x * 256 + threadIdx.x; i < e; i += gridDim.x * 256)
        rank[i] = atomicAdd(deg + dst[i], 1);
}

__global__ __launch_bounds__(256)
void blocksum_kernel(const int* __restrict__ deg, int* __restrict__ bsum, int n) {
    __shared__ int ls[256];
    const int chunk = (n + gridDim.x - 1) / gridDim.x;
    const int b0 = blockIdx.x * chunk;
    const int b1 = (b0 + chunk < n) ? b0 + chunk : n;
    int s = 0;
    for (int i = b0 + threadIdx.x; i < b1; i += 256) s += deg[i];
    ls[threadIdx.x] = s;
    __syncthreads();
    for (int off = 128; off > 0; off >>= 1) {
        if (threadIdx.x < off) ls[threadIdx.x] += ls[threadIdx.x + off];
        __syncthreads();
    }
    if (threadIdx.x == 0) bsum[blockIdx.x] = ls[0];
}

__global__ __launch_bounds__(256)
void scanb_kernel(const int* __restrict__ bsum, int* __restrict__ boff,
                  int* __restrict__ total, int nb) {
    __shared__ int ls[256];
    const int t = threadIdx.x;
    int v = (t < nb) ? bsum[t] : 0;
    ls[t] = v;
    __syncthreads();
    for (int off = 1; off < 256; off <<= 1) {
        int u = (t >= off) ? ls[t - off] : 0;
        __syncthreads();
        ls[t] += u;
        __syncthreads();
    }
    if (t < nb) boff[t] = ls[t] - v;
    if (t == 255) *total = ls[255];
}

__global__ __launch_bounds__(256)
void writeptr_kernel(const int* __restrict__ deg, const int* __restrict__ boff,
                     int* __restrict__ rowptr, int n) {
    __shared__ int ls[256];
    const int chunk = (n + gridDim.x - 1) / gridDim.x;
    const int b0 = blockIdx.x * chunk;
    const int b1 = (b0 + chunk < n) ? b0 + chunk : n;
    const int tchunk = (chunk + 255) / 256;
    const int t0 = b0 + threadIdx.x * tchunk;
    const int t1 = (t0 + tchunk < b1) ? t0 + tchunk : b1;
    int s = 0;
    for (int i = t0; i < t1; ++i) s += deg[i];
    ls[threadIdx.x] = s;
    __syncthreads();
    for (int off = 1; off < 256; off <<= 1) {
        int u = (threadIdx.x >= off) ? ls[threadIdx.x - off] : 0;
        __syncthreads();
        ls[threadIdx.x] += u;
        __syncthreads();
    }
    int run = boff[blockIdx.x] + ls[threadIdx.x] - s;
    for (int i = t0; i < t1; ++i) { rowptr[i] = run; run += deg[i]; }
}

__global__ __launch_bounds__(256)
void fill_pack_kernel(const int* __restrict__ src, const int* __restrict__ dst,
                      const float* __restrict__ eattr,
                      const int* __restrict__ rowptr, const int* __restrict__ rank,
                      int2* __restrict__ ecsr, int e) {
    for (int i = blockIdx.x * 256 + threadIdx.x; i < e; i += gridDim.x * 256) {
        int p = rowptr[dst[i]] + rank[i];
        ecsr[p] = make_int2(src[i], __float_as_int(eattr[i]));
    }
}

// ---------- linear4_dot: q | s (fp32) + kv (__half2), row-per-thread ----------
// 64-thread blocks, 2 rows/thread. Weights fp16 in LDS [4C][FIN]:
// rows [0,C)=q, [C,2C)=s, [2C,3C)=k, [3C,4C)=v. Reads are wave-uniform b128.
template<int FIN, int C>
__global__ __launch_bounds__(64)
void linear4_dot_kernel(const float* __restrict__ X,
                        const float* __restrict__ Wq, const float* __restrict__ bq,
                        const float* __restrict__ Wk, const float* __restrict__ bk,
                        const float* __restrict__ Wv, const float* __restrict__ bv,
                        const float* __restrict__ Ws, const float* __restrict__ bs,
                        float* __restrict__ q, __half2* __restrict__ kv,
                        float* __restrict__ s, int n)
{
    constexpr int FOURC = 4 * C;
    __shared__ _Float16 wflat[FOURC * FIN] __attribute__((aligned(16)));
    __shared__ float bsh[FOURC];
    const int tid = threadIdx.x;
    for (int i = tid; i < FOURC * FIN; i += 64) {
        int col = i / FIN, f = i - (i / FIN) * FIN;
        float w;
        if (col < C)          w = Wq[f * C + col];
        else if (col < 2 * C) w = Ws[f * C + col - C];
        else if (col < 3 * C) w = Wk[f * C + col - 2 * C];
        else                  w = Wv[f * C + col - 3 * C];
        wflat[i] = (_Float16)w;
    }
    for (int i = tid; i < FOURC; i += 64) {
        bsh[i] = (i < C) ? bq[i] : (i < 2 * C) ? bs[i - C]
               : (i < 3 * C) ? bk[i - 2 * C] : bv[i - 3 * C];
    }
    __syncthreads();

    const int rA = blockIdx.x * 128 + tid;
    const int rB = rA + 64;
    h2 xa[FIN / 2], xb[FIN / 2];
    if (rA < n) {
        #pragma unroll
        for (int f4 = 0; f4 < FIN / 4; ++f4) {
            float4 t = *reinterpret_cast<const float4*>(X + (size_t)rA * FIN + f4 * 4);
            xa[f4 * 2]     = h2{(_Float16)t.x, (_Float16)t.y};
            xa[f4 * 2 + 1] = h2{(_Float16)t.z, (_Float16)t.w};
        }
    }
    if (rB < n) {
        #pragma unroll
        for (int f4 = 0; f4 < FIN / 4; ++f4) {
            float4 t = *reinterpret_cast<const float4*>(X + (size_t)rB * FIN + f4 * 4);
            xb[f4 * 2]     = h2{(_Float16)t.x, (_Float16)t.y};
            xb[f4 * 2 + 1] = h2{(_Float16)t.z, (_Float16)t.w};
        }
    }

    // ---- q and s segments: 32-col chunks ----
    #pragma unroll
    for (int seg = 0; seg < 2; ++seg) {
        float* outp = seg ? s : q;
        for (int cb = 0; cb < C; cb += 32) {
            const int base = seg * C + cb;
            float accA[32], accB[32];
            #pragma unroll
            for (int j = 0; j < 32; ++j) { accA[j] = bsh[base + j]; accB[j] = accA[j]; }
            for (int f8 = 0; f8 < FIN / 8; ++f8) {
                #pragma unroll
                for (int j = 0; j < 32; ++j) {
                    h8 w = *reinterpret_cast<const h8*>(&wflat[(base + j) * FIN + f8 * 8]);
                    h2 w0 = __builtin_shufflevector(w, w, 0, 1);
                    h2 w1 = __builtin_shufflevector(w, w, 2, 3);
                    h2 w2 = __builtin_shufflevector(w, w, 4, 5);
                    h2 w3 = __builtin_shufflevector(w, w, 6, 7);
                    accA[j] = dot2(xa[f8 * 4 + 0], w0, accA[j]);
                    accA[j] = dot2(xa[f8 * 4 + 1], w1, accA[j]);
                    accA[j] = dot2(xa[f8 * 4 + 2], w2, accA[j]);
                    accA[j] = dot2(xa[f8 * 4 + 3], w3, accA[j]);
                    accB[j] = dot2(xb[f8 * 4 + 0], w0, accB[j]);
                    accB[j] = dot2(xb[f8 * 4 + 1], w1, accB[j]);
                    accB[j] = dot2(xb[f8 * 4 + 2], w2, accB[j]);
                    accB[j] = dot2(xb[f8 * 4 + 3], w3, accB[j]);
                }
            }
            if (rA < n) {
                #pragma unroll
                for (int j4 = 0; j4 < 8; ++j4)
                    *reinterpret_cast<float4*>(outp + (size_t)rA * C + cb + j4 * 4) =
                        make_float4(accA[j4*4], accA[j4*4+1], accA[j4*4+2], accA[j4*4+3]);
            }
            if (rB < n) {
                #pragma unroll
                for (int j4 = 0; j4 < 8; ++j4)
                    *reinterpret_cast<float4*>(outp + (size_t)rB * C + cb + j4 * 4) =
                        make_float4(accB[j4*4], accB[j4*4+1], accB[j4*4+2], accB[j4*4+3]);
            }
        }
    }

    // ---- kv segment: 16-col chunks, k and v together, packed __half2 ----
    for (int cb = 0; cb < C; cb += 16) {
        float accKA[16], accVA[16], accKB[16], accVB[16];
        #pragma unroll
        for (int j = 0; j < 16; ++j) {
            accKA[j] = bsh[2 * C + cb + j]; accKB[j] = accKA[j];
            accVA[j] = bsh[3 * C + cb + j]; accVB[j] = accVA[j];
        }
        for (int f8 = 0; f8 < FIN / 8; ++f8) {
            #pragma unroll
            for (int j = 0; j < 16; ++j) {
                h8 wk = *reinterpret_cast<const h8*>(&wflat[(2 * C + cb + j) * FIN + f8 * 8]);
                h8 wv = *reinterpret_cast<const h8*>(&wflat[(3 * C + cb + j) * FIN + f8 * 8]);
                h2 k0 = __builtin_shufflevector(wk, wk, 0, 1);
                h2 k1 = __builtin_shufflevector(wk, wk, 2, 3);
                h2 k2 = __builtin_shufflevector(wk, wk, 4, 5);
                h2 k3 = __builtin_shufflevector(wk, wk, 6, 7);
                h2 v0 = __builtin_shufflevector(wv, wv, 0, 1);
                h2 v1 = __builtin_shufflevector(wv, wv, 2, 3);
                h2 v2 = __builtin_shufflevector(wv, wv, 4, 5);
                h2 v3 = __builtin_shufflevector(wv, wv, 6, 7);
                accKA[j] = dot2(xa[f8*4+0], k0, accKA[j]);
                accKA[j] = dot2(xa[f8*4+1], k1, accKA[j]);
                accKA[j] = dot2(xa[f8*4+2], k2, accKA[j]);
                accKA[j] = dot2(xa[f8*4+3], k3, accKA[j]);
                accVA[j] = dot2(xa[f8*4+0], v0, accVA[j]);
                accVA[j] = dot2(xa[f8*4+1], v1, accVA[j]);
                accVA[j] = dot2(xa[f8*4+2], v2, accVA[j]);
                accVA[j] = dot2(xa[f8*4+3], v3, accVA[j]);
                accKB[j] = dot2(xb[f8*4+0], k0, accKB[j]);
                accKB[j] = dot2(xb[f8*4+1], k1, accKB[j]);
                accKB[j] = dot2(xb[f8*4+2], k2, accKB[j]);
                accKB[j] = dot2(xb[f8*4+3], k3, accKB[j]);
                accVB[j] = dot2(xb[f8*4+0], v0, accVB[j]);
                accVB[j] = dot2(xb[f8*4+1], v1, accVB[j]);
                accVB[j] = dot2(xb[f8*4+2], v2, accVB[j]);
                accVB[j] = dot2(xb[f8*4+3], v3, accVB[j]);
            }
        }
        if (rA < n) {
            #pragma unroll
            for (int j = 0; j < 16; ++j)
                kv[(size_t)rA * C + cb + j] = __floats2half2_rn(accKA[j], accVA[j]);
        }
        if (rB < n) {
            #pragma unroll
            for (int j = 0; j < 16; ++j)
                kv[(size_t)rB * C + cb + j] = __floats2half2_rn(accKB[j], accVB[j]);
        }
    }
}

// ---------- linear_dot (fc1): fp32 out + optional ELU, same structure ----------
template<int FIN, int COUT, bool ELU>
__global__ __launch_bounds__(64)
void linear_dot_kernel(const float* __restrict__ X, const float* __restrict__ W,
                       const float* __restrict__ b, float* __restrict__ out, int n)
{
    __shared__ _Float16 wflat[COUT * FIN] __attribute__((aligned(16)));
    __shared__ float bsh[COUT];
    const int tid = threadIdx.x;
    for (int i = tid; i < COUT * FIN; i += 64) {
        int col = i / FIN, f = i - (i / FIN) * FIN;
        wflat[i] = (_Float16)W[f * COUT + col];
    }
    for (int i = tid; i < COUT; i += 64) bsh[i] = b[i];
    __syncthreads();

    const int rA = blockIdx.x * 128 + tid;
    const int rB = rA + 64;
    h2 xa[FIN / 2], xb[FIN / 2];
    if (rA < n) {
        #pragma unroll
        for (int f4 = 0; f4 < FIN / 4; ++f4) {
            float4 t = *reinterpret_cast<const float4*>(X + (size_t)rA * FIN + f4 * 4);
            xa[f4 * 2]     = h2{(_Float16)t.x, (_Float16)t.y};
            xa[f4 * 2 + 1] = h2{(_Float16)t.z, (_Float16)t.w};
        }
    }
    if (rB < n) {
        #pragma unroll
        for (int f4 = 0; f4 < FIN / 4; ++f4) {
            float4 t = *reinterpret_cast<const float4*>(X + (size_t)rB * FIN + f4 * 4);
            xb[f4 * 2]     = h2{(_Float16)t.x, (_Float16)t.y};
            xb[f4 * 2 + 1] = h2{(_Float16)t.z, (_Float16)t.w};
        }
    }

    for (int cb = 0; cb < COUT; cb += 32) {
        float accA[32], accB[32];
        #pragma unroll
        for (int j = 0; j < 32; ++j) { accA[j] = bsh[cb + j]; accB[j] = accA[j]; }
        for (int f8 = 0; f8 < FIN / 8; ++f8) {
            #pragma unroll
            for (int j = 0; j < 32; ++j) {
                h8 w = *reinterpret_cast<const h8*>(&wflat[(cb + j) * FIN + f8 * 8]);
                h2 w0 = __builtin_shufflevector(w, w, 0, 1);
                h2 w1 = __builtin_shufflevector(w, w, 2, 3);
                h2 w2 = __builtin_shufflevector(w, w, 4, 5);
                h2 w3 = __builtin_shufflevector(w, w, 6, 7);
                accA[j] = dot2(xa[f8*4+0], w0, accA[j]);
                accA[j] = dot2(xa[f8*4+1], w1, accA[j]);
                accA[j] = dot2(xa[f8*4+2], w2, accA[j]);
                accA[j] = dot2(xa[f8*4+3], w3, accA[j]);
                accB[j] = dot2(xb[f8*4+0], w0, accB[j]);
                accB[j] = dot2(xb[f8*4+1], w1, accB[j]);
                accB[j] = dot2(xb[f8*4+2], w2, accB[j]);
                accB[j] = dot2(xb[f8*4+3], w3, accB[j]);
            }
        }
        if (ELU) {
            #pragma unroll
            for (int j = 0; j < 32; ++j) {
                accA[j] = (accA[j] > 0.f) ? accA[j] : expm1f(accA[j]);
                accB[j] = (accB[j] > 0.f) ? accB[j] : expm1f(accB[j]);
            }
        }
        if (rA < n) {
            #pragma unroll
            for (int j4 = 0; j4 < 8; ++j4)
                *reinterpret_cast<float4*>(out + (size_t)rA * COUT + cb + j4 * 4) =
                    make_float4(accA[j4*4], accA[j4*4+1], accA[j4*4+2], accA[j4*4+3]);
        }
        if (rB < n) {
            #pragma unroll
            for (int j4 = 0; j4 < 8; ++j4)
                *reinterpret_cast<float4*>(out + (size_t)rB * COUT + cb + j4 * 4) =
                    make_float4(accB[j4*4], accB[j4*4+1], accB[j4*4+2], accB[j4*4+3]);
        }
    }
}

// ---------- fused conv: per-node softmax (no max shift) + aggregation + skip + ELU ----------
template<int C>
__global__ __launch_bounds__(256)
void conv_fused_kernel(const int* __restrict__ rowptr, const int2* __restrict__ ecsr,
                       const float* __restrict__ q, const __half2* __restrict__ kv,
                       const float* __restrict__ sres,
                       const float* __restrict__ We, const float* __restrict__ be,
                       float* __restrict__ h, float scale, int n)
{
    constexpr int EPI    = 64 / C;
    constexpr int UNROLL = (C == 64) ? 4 : 2;
    constexpr int LOGC   = (C == 64) ? 6 : 5;
    const int wave = threadIdx.x >> 6;
    const int lane = threadIdx.x & 63;
    const int c    = lane & (C - 1);
    const int slot = lane >> LOGC;
    const int node = blockIdx.x * 4 + wave;
    if (node >= n) return;

    const float wec = We[c], bec = be[c];
    const float qc  = q[(size_t)node * C + c];
    const int r0 = rowptr[node], r1 = rowptr[node + 1];

    float ssum = 0.f, acc = 0.f;
    int j = r0 + slot;
    for (; j + (UNROLL - 1) * EPI < r1; j += UNROLL * EPI) {
        int2 epk[UNROLL]; __half2 f[UNROLL];
        #pragma unroll
        for (int u = 0; u < UNROLL; ++u) epk[u] = ecsr[j + u * EPI];
        #pragma unroll
        for (int u = 0; u < UNROLL; ++u) f[u] = kv[(size_t)epk[u].x * C + c];
        #pragma unroll
        for (int u = 0; u < UNROLL; ++u) {
            float2 fv = __half22float2(f[u]);
            float ec = fmaf(__int_as_float(epk[u].y), wec, bec);
            float p = qc * (fv.x + ec);
            #pragma unroll
            for (int off = C >> 1; off > 0; off >>= 1) p += __shfl_xor(p, off, C);
            float w = __expf(p * scale);
            ssum += w;
            acc = fmaf(w, fv.y + ec, acc);
        }
    }
    for (; j < r1; j += EPI) {
        int2 epk = ecsr[j];
        float2 fv = __half22float2(kv[(size_t)epk.x * C + c]);
        float ec = fmaf(__int_as_float(epk.y), wec, bec);
        float p = qc * (fv.x + ec);
        #pragma unroll
        for (int off = C >> 1; off > 0; off >>= 1) p += __shfl_xor(p, off, C);
        float w = __expf(p * scale);
        ssum += w;
        acc = fmaf(w, fv.y + ec, acc);
    }

    if constexpr (EPI == 2) {
        ssum += __shfl_xor(ssum, 32);
        acc  += __shfl_xor(acc, 32);
    }

    if (slot == 0) {
        float outv = acc / (ssum + 1e-16f);
        float hv = outv + sres[(size_t)node * C + c];
        h[(size_t)node * C + c] = (hv > 0.f) ? hv : expm1f(hv);
    }
}

// ---------- fc2 + log_softmax ----------
#define H1_DIM 128
#define NC_DIM 10
__global__ __launch_bounds__(256)
void head_kernel(const float* __restrict__ Hf, const float* __restrict__ W,
                 const float* __restrict__ b, float* __restrict__ out, int n)
{
    __shared__ float wsh[H1_DIM * NC_DIM];
    __shared__ float bsh[NC_DIM];
    for (int i = threadIdx.x; i < H1_DIM * NC_DIM; i += 256) wsh[i] = W[i];
    for (int i = threadIdx.x; i < NC_DIM; i += 256) bsh[i] = b[i];
    __syncthreads();
    for (int row = blockIdx.x * 256 + threadIdx.x; row < n; row += gridDim.x * 256) {
        const float* hr = Hf + (size_t)row * H1_DIM;
        float logit[NC_DIM];
        #pragma unroll
        for (int c = 0; c < NC_DIM; ++c) logit[c] = bsh[c];
        for (int f = 0; f < H1_DIM; ++f) {
            float xv = hr[f];
            #pragma unroll
            for (int c = 0; c < NC_DIM; ++c) logit[c] = fmaf(xv, wsh[f * NC_DIM + c], logit[c]);
        }
        float m = logit[0];
        #pragma unroll
        for (int c = 1; c < NC_DIM; ++c) m = fmaxf(m, logit[c]);
        float sum = 0.f;
        #pragma unroll
        for (int c = 0; c < NC_DIM; ++c) sum += __expf(logit[c] - m);
        float lse = m + logf(sum);
        #pragma unroll
        for (int c = 0; c < NC_DIM; ++c) out[(size_t)row * NC_DIM + c] = logit[c] - lse;
    }
}

extern "C" void kernel_launch(void* const* d_in, const int* in_sizes, int n_in,
                              void* d_out, int out_size, void* d_ws, size_t ws_size,
                              hipStream_t stream) {
    const float* x   = (const float*)d_in[0];
    const int*   ei  = (const int*)d_in[1];
    const float* ea  = (const float*)d_in[2];
    const float *Wq1 = (const float*)d_in[3],  *bq1 = (const float*)d_in[4];
    const float *Wk1 = (const float*)d_in[5],  *bk1 = (const float*)d_in[6];
    const float *Wv1 = (const float*)d_in[7],  *bv1 = (const float*)d_in[8];
    const float *We1 = (const float*)d_in[9],  *be1 = (const float*)d_in[10];
    const float *Ws1 = (const float*)d_in[11], *bs1 = (const float*)d_in[12];
    const float *Wq2 = (const float*)d_in[13], *bq2 = (const float*)d_in[14];
    const float *Wk2 = (const float*)d_in[15], *bk2 = (const float*)d_in[16];
    const float *Wv2 = (const float*)d_in[17], *bv2 = (const float*)d_in[18];
    const float *We2 = (const float*)d_in[19], *be2 = (const float*)d_in[20];
    const float *Ws2 = (const float*)d_in[21], *bs2 = (const float*)d_in[22];
    const float *Wf1 = (const float*)d_in[23], *bf1 = (const float*)d_in[24];
    const float *Wf2 = (const float*)d_in[25], *bf2 = (const float*)d_in[26];

    const int N = in_sizes[0] / 64;   // 100000
    const int E = in_sizes[2];        // 1600000
    const int* src = ei;              // edge_index[0]
    const int* dst = ei + E;          // edge_index[1]

    float* wsf = (float*)d_ws;
    const size_t N64 = (size_t)N * 64;
    float* q      = wsf;                      // N*64
    __half2* kv   = (__half2*)(q + N64);      // N*64 half2 (k,v packed)
    float* s      = (float*)(kv + N64);       // N*64 (skip proj)
    float* h1     = s + N64;                  // N*32
    float* h2     = h1 + (size_t)N * 32;      // N*64
    int* deg      = (int*)(h2 + N64);         // N
    int* rowptr   = deg + N;                  // N+1
    int* bsum     = rowptr + N + 1;           // SCAN_NB
    int* boff     = bsum + SCAN_NB;           // SCAN_NB
    int* rank     = boff + SCAN_NB;           // E
    int2* ecsr    = (int2*)(rank + E);        // E (packed {src, eattr})
    float* hfc    = wsf;                      // N*128 (reuses dead q after conv2)

    float* out = (float*)d_out;

    // ---- CSR build ----
    hipMemsetAsync(deg, 0, (size_t)N * 4, stream);
    count_rank_kernel<<<2048, 256, 0, stream>>>(dst, deg, rank, E);
    blocksum_kernel<<<SCAN_NB, 256, 0, stream>>>(deg, bsum, N);
    scanb_kernel<<<1, 256, 0, stream>>>(bsum, boff, rowptr + N, SCAN_NB);
    writeptr_kernel<<<SCAN_NB, 256, 0, stream>>>(deg, boff, rowptr, N);
    fill_pack_kernel<<<4096, 256, 0, stream>>>(src, dst, ea, rowptr, rank, ecsr, E);

    const int convGrid = (N + 3) / 4;
    const int rowGrid  = (N + 127) / 128;

    // ---- layer 1 (C=32) ----
    linear4_dot_kernel<64, 32><<<rowGrid, 64, 0, stream>>>(
        x, Wq1, bq1, Wk1, bk1, Wv1, bv1, Ws1, bs1, q, kv, s, N);
    conv_fused_kernel<32><<<convGrid, 256, 0, stream>>>(
        rowptr, ecsr, q, kv, s, We1, be1, h1, 0.17677669529663687f, N);

    // ---- layer 2 (C=64) ----
    linear4_dot_kernel<32, 64><<<rowGrid, 64, 0, stream>>>(
        h1, Wq2, bq2, Wk2, bk2, Wv2, bv2, Ws2, bs2, q, kv, s, N);
    conv_fused_kernel<64><<<convGrid, 256, 0, stream>>>(
        rowptr, ecsr, q, kv, s, We2, be2, h2, 0.125f, N);

    // ---- MLP head ----
    linear_dot_kernel<64, 128, true><<<rowGrid, 64, 0, stream>>>(h2, Wf1, bf1, hfc, N);
    head_kernel<<<512, 256, 0, stream>>>(hfc, Wf2, bf2, out, N);
}

// Round 10
// 402.873 us; speedup vs baseline: 3.3988x; 3.3988x over previous
//
#include <hip/hip_runtime.h>
#include <hip/hip_fp16.h>
#include <math.h>

// TransformerConvNet: 2x TransformerConv(heads=1) + ELU + MLP head + log_softmax
// N=100000 nodes, E=1600000 edges, F_IN=64, C1=32, C2=64, H1=128, NC=10
//
// R9 (resubmit after infra failure): dense linears on MFMA (16x16x32 f16).
// B-frags live in VGPRs across a grid-stride row loop; 16-row tile per wave;
// 4096 waves (fixes R8's 782-wave occupancy collapse). k-order inside frags is
// self-consistent A/B so only the verified lane&15 row/col + C/D maps matter.

#define SCAN_NB 256

typedef _Float16 half8 __attribute__((ext_vector_type(8)));
typedef float f32x4 __attribute__((ext_vector_type(4)));

// ---------- CSR build ----------
__global__ __launch_bounds__(256)
void count_rank_kernel(const int* __restrict__ dst, int* __restrict__ deg,
                       int* __restrict__ rank, int e) {
    for (int i = blockIdx.x * 256 + threadIdx.x; i < e; i += gridDim.x * 256)
        rank[i] = atomicAdd(deg + dst[i], 1);
}

__global__ __launch_bounds__(256)
void blocksum_kernel(const int* __restrict__ deg, int* __restrict__ bsum, int n) {
    __shared__ int ls[256];
    const int chunk = (n + gridDim.x - 1) / gridDim.x;
    const int b0 = blockIdx.x * chunk;
    const int b1 = (b0 + chunk < n) ? b0 + chunk : n;
    int s = 0;
    for (int i = b0 + threadIdx.x; i < b1; i += 256) s += deg[i];
    ls[threadIdx.x] = s;
    __syncthreads();
    for (int off = 128; off > 0; off >>= 1) {
        if (threadIdx.x < off) ls[threadIdx.x] += ls[threadIdx.x + off];
        __syncthreads();
    }
    if (threadIdx.x == 0) bsum[blockIdx.x] = ls[0];
}

__global__ __launch_bounds__(256)
void scanb_kernel(const int* __restrict__ bsum, int* __restrict__ boff,
                  int* __restrict__ total, int nb) {
    __shared__ int ls[256];
    const int t = threadIdx.x;
    int v = (t < nb) ? bsum[t] : 0;
    ls[t] = v;
    __syncthreads();
    for (int off = 1; off < 256; off <<= 1) {
        int u = (t >= off) ? ls[t - off] : 0;
        __syncthreads();
        ls[t] += u;
        __syncthreads();
    }
    if (t < nb) boff[t] = ls[t] - v;
    if (t == 255) *total = ls[255];
}

__global__ __launch_bounds__(256)
void writeptr_kernel(const int* __restrict__ deg, const int* __restrict__ boff,
                     int* __restrict__ rowptr, int n) {
    __shared__ int ls[256];
    const int chunk = (n + gridDim.x - 1) / gridDim.x;
    const int b0 = blockIdx.x * chunk;
    const int b1 = (b0 + chunk < n) ? b0 + chunk : n;
    const int tchunk = (chunk + 255) / 256;
    const int t0 = b0 + threadIdx.x * tchunk;
    const int t1 = (t0 + tchunk < b1) ? t0 + tchunk : b1;
    int s = 0;
    for (int i = t0; i < t1; ++i) s += deg[i];
    ls[threadIdx.x] = s;
    __syncthreads();
    for (int off = 1; off < 256; off <<= 1) {
        int u = (threadIdx.x >= off) ? ls[threadIdx.x - off] : 0;
        __syncthreads();
        ls[threadIdx.x] += u;
        __syncthreads();
    }
    int run = boff[blockIdx.x] + ls[threadIdx.x] - s;
    for (int i = t0; i < t1; ++i) { rowptr[i] = run; run += deg[i]; }
}

__global__ __launch_bounds__(256)
void fill_pack_kernel(const int* __restrict__ src, const int* __restrict__ dst,
                      const float* __restrict__ eattr,
                      const int* __restrict__ rowptr, const int* __restrict__ rank,
                      int2* __restrict__ ecsr, int e) {
    for (int i = blockIdx.x * 256 + threadIdx.x; i < e; i += gridDim.x * 256) {
        int p = rowptr[dst[i]] + rank[i];
        ecsr[p] = make_int2(src[i], __float_as_int(eattr[i]));
    }
}

// ---------- linear4 via MFMA: q | s (fp32) + kv (__half2) ----------
// LDS weights fp16, layout wsh[col*P + f], col in [0,4C): q|s|k|v. P=FIN+16.
// Per wave: B-frags in VGPRs, grid-stride over 16-row tiles.
template<int FIN, int C>
__global__ __launch_bounds__(256, 2)
void linear4_mfma_kernel(const float* __restrict__ X,
                         const float* __restrict__ Wq, const float* __restrict__ bq,
                         const float* __restrict__ Wk, const float* __restrict__ bk,
                         const float* __restrict__ Wv, const float* __restrict__ bv,
                         const float* __restrict__ Ws, const float* __restrict__ bs,
                         float* __restrict__ q, __half2* __restrict__ kv,
                         float* __restrict__ s, int n)
{
    constexpr int FOURC = 4 * C;
    constexpr int P  = FIN + 16;     // LDS pitch (halfs): 16B-aligned rows, bank-spread
    constexpr int KT = FIN / 32;     // k tiles
    constexpr int NT = FOURC / 16;   // n tiles
    __shared__ _Float16 wsh[FOURC * P] __attribute__((aligned(16)));
    __shared__ float bsh[FOURC];

    for (int i = threadIdx.x; i < FOURC * FIN; i += 256) {
        int col = i / FIN, f = i - (i / FIN) * FIN;
        float w;
        if (col < C)          w = Wq[f * C + col];
        else if (col < 2 * C) w = Ws[f * C + col - C];
        else if (col < 3 * C) w = Wk[f * C + col - 2 * C];
        else                  w = Wv[f * C + col - 3 * C];
        wsh[col * P + f] = (_Float16)w;
    }
    for (int i = threadIdx.x; i < FOURC; i += 256) {
        bsh[i] = (i < C) ? bq[i] : (i < 2 * C) ? bs[i - C]
               : (i < 3 * C) ? bk[i - 2 * C] : bv[i - 3 * C];
    }
    __syncthreads();

    const int lane = threadIdx.x & 63;
    const int wid  = threadIdx.x >> 6;
    const int m = lane & 15, g = lane >> 4;

    half8 bfrag[KT][NT];
    #pragma unroll
    for (int kt = 0; kt < KT; ++kt)
        #pragma unroll
        for (int nt = 0; nt < NT; ++nt)
            bfrag[kt][nt] = *reinterpret_cast<const half8*>(
                &wsh[(nt * 16 + m) * P + kt * 32 + g * 8]);

    const int tiles = n >> 4;   // N divisible by 16 (100000 = 6250*16)
    for (int t = blockIdx.x * 4 + wid; t < tiles; t += gridDim.x * 4) {
        const int row0 = t * 16;
        const float* xr = X + (size_t)(row0 + m) * FIN + g * 8;
        half8 afrag[KT];
        #pragma unroll
        for (int kt = 0; kt < KT; ++kt) {
            float4 u = *reinterpret_cast<const float4*>(xr + kt * 32);
            float4 w = *reinterpret_cast<const float4*>(xr + kt * 32 + 4);
            afrag[kt] = half8{(_Float16)u.x, (_Float16)u.y, (_Float16)u.z, (_Float16)u.w,
                              (_Float16)w.x, (_Float16)w.y, (_Float16)w.z, (_Float16)w.w};
        }
        // q and s segments (fp32 out)
        #pragma unroll
        for (int nt = 0; nt < 2 * C / 16; ++nt) {
            f32x4 acc = {0.f, 0.f, 0.f, 0.f};
            #pragma unroll
            for (int kt = 0; kt < KT; ++kt)
                acc = __builtin_amdgcn_mfma_f32_16x16x32_f16(afrag[kt], bfrag[kt][nt], acc, 0, 0, 0);
            const int col = nt * 16 + m;
            const float bias = bsh[col];
            float* outp = (nt < C / 16) ? q : s;
            const int cc = (nt < C / 16) ? col : col - C;
            #pragma unroll
            for (int r = 0; r < 4; ++r)
                outp[(size_t)(row0 + g * 4 + r) * C + cc] = acc[r] + bias;
        }
        // kv segment (packed __half2)
        #pragma unroll
        for (int t2 = 0; t2 < C / 16; ++t2) {
            const int ntK = 2 * C / 16 + t2, ntV = 3 * C / 16 + t2;
            f32x4 aK = {0.f, 0.f, 0.f, 0.f}, aV = {0.f, 0.f, 0.f, 0.f};
            #pragma unroll
            for (int kt = 0; kt < KT; ++kt) {
                aK = __builtin_amdgcn_mfma_f32_16x16x32_f16(afrag[kt], bfrag[kt][ntK], aK, 0, 0, 0);
                aV = __builtin_amdgcn_mfma_f32_16x16x32_f16(afrag[kt], bfrag[kt][ntV], aV, 0, 0, 0);
            }
            const int ck = t2 * 16 + m;
            const float bK = bsh[2 * C + ck], bV = bsh[3 * C + ck];
            #pragma unroll
            for (int r = 0; r < 4; ++r)
                kv[(size_t)(row0 + g * 4 + r) * C + ck] = __floats2half2_rn(aK[r] + bK, aV[r] + bV);
        }
    }
}

// ---------- fc1 via MFMA: fp32 out + ELU ----------
template<int FIN, int COUT>
__global__ __launch_bounds__(256, 2)
void linear_mfma_kernel(const float* __restrict__ X, const float* __restrict__ W,
                        const float* __restrict__ b, float* __restrict__ out, int n)
{
    constexpr int P  = FIN + 16;
    constexpr int KT = FIN / 32;
    constexpr int NT = COUT / 16;
    __shared__ _Float16 wsh[COUT * P] __attribute__((aligned(16)));
    __shared__ float bsh[COUT];
    for (int i = threadIdx.x; i < COUT * FIN; i += 256) {
        int col = i / FIN, f = i - (i / FIN) * FIN;
        wsh[col * P + f] = (_Float16)W[f * COUT + col];
    }
    for (int i = threadIdx.x; i < COUT; i += 256) bsh[i] = b[i];
    __syncthreads();

    const int lane = threadIdx.x & 63;
    const int wid  = threadIdx.x >> 6;
    const int m = lane & 15, g = lane >> 4;

    half8 bfrag[KT][NT];
    #pragma unroll
    for (int kt = 0; kt < KT; ++kt)
        #pragma unroll
        for (int nt = 0; nt < NT; ++nt)
            bfrag[kt][nt] = *reinterpret_cast<const half8*>(
                &wsh[(nt * 16 + m) * P + kt * 32 + g * 8]);

    const int tiles = n >> 4;
    for (int t = blockIdx.x * 4 + wid; t < tiles; t += gridDim.x * 4) {
        const int row0 = t * 16;
        const float* xr = X + (size_t)(row0 + m) * FIN + g * 8;
        half8 afrag[KT];
        #pragma unroll
        for (int kt = 0; kt < KT; ++kt) {
            float4 u = *reinterpret_cast<const float4*>(xr + kt * 32);
            float4 w = *reinterpret_cast<const float4*>(xr + kt * 32 + 4);
            afrag[kt] = half8{(_Float16)u.x, (_Float16)u.y, (_Float16)u.z, (_Float16)u.w,
                              (_Float16)w.x, (_Float16)w.y, (_Float16)w.z, (_Float16)w.w};
        }
        #pragma unroll
        for (int nt = 0; nt < NT; ++nt) {
            f32x4 acc = {0.f, 0.f, 0.f, 0.f};
            #pragma unroll
            for (int kt = 0; kt < KT; ++kt)
                acc = __builtin_amdgcn_mfma_f32_16x16x32_f16(afrag[kt], bfrag[kt][nt], acc, 0, 0, 0);
            const int col = nt * 16 + m;
            const float bias = bsh[col];
            #pragma unroll
            for (int r = 0; r < 4; ++r) {
                float hv = acc[r] + bias;
                hv = (hv > 0.f) ? hv : expm1f(hv);
                out[(size_t)(row0 + g * 4 + r) * COUT + col] = hv;
            }
        }
    }
}

// ---------- fused conv: per-node softmax (no max shift) + aggregation + skip + ELU ----------
template<int C>
__global__ __launch_bounds__(256)
void conv_fused_kernel(const int* __restrict__ rowptr, const int2* __restrict__ ecsr,
                       const float* __restrict__ q, const __half2* __restrict__ kv,
                       const float* __restrict__ sres,
                       const float* __restrict__ We, const float* __restrict__ be,
                       float* __restrict__ h, float scale, int n)
{
    constexpr int EPI    = 64 / C;
    constexpr int UNROLL = (C == 64) ? 4 : 2;
    constexpr int LOGC   = (C == 64) ? 6 : 5;
    const int wave = threadIdx.x >> 6;
    const int lane = threadIdx.x & 63;
    const int c    = lane & (C - 1);
    const int slot = lane >> LOGC;
    const int node = blockIdx.x * 4 + wave;
    if (node >= n) return;

    const float wec = We[c], bec = be[c];
    const float qc  = q[(size_t)node * C + c];
    const int r0 = rowptr[node], r1 = rowptr[node + 1];

    float ssum = 0.f, acc = 0.f;
    int j = r0 + slot;
    for (; j + (UNROLL - 1) * EPI < r1; j += UNROLL * EPI) {
        int2 epk[UNROLL]; __half2 f[UNROLL];
        #pragma unroll
        for (int u = 0; u < UNROLL; ++u) epk[u] = ecsr[j + u * EPI];
        #pragma unroll
        for (int u = 0; u < UNROLL; ++u) f[u] = kv[(size_t)epk[u].x * C + c];
        #pragma unroll
        for (int u = 0; u < UNROLL; ++u) {
            float2 fv = __half22float2(f[u]);
            float ec = fmaf(__int_as_float(epk[u].y), wec, bec);
            float p = qc * (fv.x + ec);
            #pragma unroll
            for (int off = C >> 1; off > 0; off >>= 1) p += __shfl_xor(p, off, C);
            float w = __expf(p * scale);
            ssum += w;
            acc = fmaf(w, fv.y + ec, acc);
        }
    }
    for (; j < r1; j += EPI) {
        int2 epk = ecsr[j];
        float2 fv = __half22float2(kv[(size_t)epk.x * C + c]);
        float ec = fmaf(__int_as_float(epk.y), wec, bec);
        float p = qc * (fv.x + ec);
        #pragma unroll
        for (int off = C >> 1; off > 0; off >>= 1) p += __shfl_xor(p, off, C);
        float w = __expf(p * scale);
        ssum += w;
        acc = fmaf(w, fv.y + ec, acc);
    }

    if constexpr (EPI == 2) {
        ssum += __shfl_xor(ssum, 32);
        acc  += __shfl_xor(acc, 32);
    }

    if (slot == 0) {
        float outv = acc / (ssum + 1e-16f);
        float hv = outv + sres[(size_t)node * C + c];
        h[(size_t)node * C + c] = (hv > 0.f) ? hv : expm1f(hv);
    }
}

// ---------- fc2 + log_softmax ----------
#define H1_DIM 128
#define NC_DIM 10
__global__ __launch_bounds__(256)
void head_kernel(const float* __restrict__ Hf, const float* __restrict__ W,
                 const float* __restrict__ b, float* __restrict__ out, int n)
{
    __shared__ float wsh[H1_DIM * NC_DIM];
    __shared__ float bsh[NC_DIM];
    for (int i = threadIdx.x; i < H1_DIM * NC_DIM; i += 256) wsh[i] = W[i];
    for (int i = threadIdx.x; i < NC_DIM; i += 256) bsh[i] = b[i];
    __syncthreads();
    for (int row = blockIdx.x * 256 + threadIdx.x; row < n; row += gridDim.x * 256) {
        const float* hr = Hf + (size_t)row * H1_DIM;
        float logit[NC_DIM];
        #pragma unroll
        for (int c = 0; c < NC_DIM; ++c) logit[c] = bsh[c];
        for (int f = 0; f < H1_DIM; ++f) {
            float xv = hr[f];
            #pragma unroll
            for (int c = 0; c < NC_DIM; ++c) logit[c] = fmaf(xv, wsh[f * NC_DIM + c], logit[c]);
        }
        float m = logit[0];
        #pragma unroll
        for (int c = 1; c < NC_DIM; ++c) m = fmaxf(m, logit[c]);
        float sum = 0.f;
        #pragma unroll
        for (int c = 0; c < NC_DIM; ++c) sum += __expf(logit[c] - m);
        float lse = m + logf(sum);
        #pragma unroll
        for (int c = 0; c < NC_DIM; ++c) out[(size_t)row * NC_DIM + c] = logit[c] - lse;
    }
}

extern "C" void kernel_launch(void* const* d_in, const int* in_sizes, int n_in,
                              void* d_out, int out_size, void* d_ws, size_t ws_size,
                              hipStream_t stream) {
    const float* x   = (const float*)d_in[0];
    const int*   ei  = (const int*)d_in[1];
    const float* ea  = (const float*)d_in[2];
    const float *Wq1 = (const float*)d_in[3],  *bq1 = (const float*)d_in[4];
    const float *Wk1 = (const float*)d_in[5],  *bk1 = (const float*)d_in[6];
    const float *Wv1 = (const float*)d_in[7],  *bv1 = (const float*)d_in[8];
    const float *We1 = (const float*)d_in[9],  *be1 = (const float*)d_in[10];
    const float *Ws1 = (const float*)d_in[11], *bs1 = (const float*)d_in[12];
    const float *Wq2 = (const float*)d_in[13], *bq2 = (const float*)d_in[14];
    const float *Wk2 = (const float*)d_in[15], *bk2 = (const float*)d_in[16];
    const float *Wv2 = (const float*)d_in[17], *bv2 = (const float*)d_in[18];
    const float *We2 = (const float*)d_in[19], *be2 = (const float*)d_in[20];
    const float *Ws2 = (const float*)d_in[21], *bs2 = (const float*)d_in[22];
    const float *Wf1 = (const float*)d_in[23], *bf1 = (const float*)d_in[24];
    const float *Wf2 = (const float*)d_in[25], *bf2 = (const float*)d_in[26];

    const int N = in_sizes[0] / 64;   // 100000
    const int E = in_sizes[2];        // 1600000
    const int* src = ei;              // edge_index[0]
    const int* dst = ei + E;          // edge_index[1]

    float* wsf = (float*)d_ws;
    const size_t N64 = (size_t)N * 64;
    float* q      = wsf;                      // N*64
    __half2* kv   = (__half2*)(q + N64);      // N*64 half2 (k,v packed)
    float* s      = (float*)(kv + N64);       // N*64 (skip proj)
    float* h1     = s + N64;                  // N*32
    float* h2     = h1 + (size_t)N * 32;      // N*64
    int* deg      = (int*)(h2 + N64);         // N
    int* rowptr   = deg + N;                  // N+1
    int* bsum     = rowptr + N + 1;           // SCAN_NB
    int* boff     = bsum + SCAN_NB;           // SCAN_NB
    int* rank     = boff + SCAN_NB;           // E
    int2* ecsr    = (int2*)(rank + E);        // E (packed {src, eattr})
    float* hfc    = wsf;                      // N*128 (reuses dead q after conv2)

    float* out = (float*)d_out;

    // ---- CSR build ----
    hipMemsetAsync(deg, 0, (size_t)N * 4, stream);
    count_rank_kernel<<<2048, 256, 0, stream>>>(dst, deg, rank, E);
    blocksum_kernel<<<SCAN_NB, 256, 0, stream>>>(deg, bsum, N);
    scanb_kernel<<<1, 256, 0, stream>>>(bsum, boff, rowptr + N, SCAN_NB);
    writeptr_kernel<<<SCAN_NB, 256, 0, stream>>>(deg, boff, rowptr, N);
    fill_pack_kernel<<<4096, 256, 0, stream>>>(src, dst, ea, rowptr, rank, ecsr, E);

    const int convGrid = (N + 3) / 4;

    // ---- layer 1 (C=32) ----
    linear4_mfma_kernel<64, 32><<<1024, 256, 0, stream>>>(
        x, Wq1, bq1, Wk1, bk1, Wv1, bv1, Ws1, bs1, q, kv, s, N);
    conv_fused_kernel<32><<<convGrid, 256, 0, stream>>>(
        rowptr, ecsr, q, kv, s, We1, be1, h1, 0.17677669529663687f, N);

    // ---- layer 2 (C=64) ----
    linear4_mfma_kernel<32, 64><<<1024, 256, 0, stream>>>(
        h1, Wq2, bq2, Wk2, bk2, Wv2, bv2, Ws2, bs2, q, kv, s, N);
    conv_fused_kernel<64><<<convGrid, 256, 0, stream>>>(
        rowptr, ecsr, q, kv, s, We2, be2, h2, 0.125f, N);

    // ---- MLP head ----
    linear_mfma_kernel<64, 128><<<1024, 256, 0, stream>>>(h2, Wf1, bf1, hfc, N);
    head_kernel<<<512, 256, 0, stream>>>(hfc, Wf2, bf2, out, N);
}

// Round 11
// 362.202 us; speedup vs baseline: 3.7804x; 1.1123x over previous
//
#include <hip/hip_runtime.h>
#include <hip/hip_fp16.h>
#include <math.h>

// TransformerConvNet: 2x TransformerConv(heads=1) + ELU + MLP head + log_softmax
// N=100000 nodes, E=1600000 edges, F_IN=64, C1=32, C2=64, H1=128, NC=10
//
// R11: conv_fused restructured to 2 channels/lane — halves per-edge VALU work
// (5-step/32-lane reduce for C=64, 2-4 edges in flight per wave, float2
// gathers). CSR build + MFMA linears unchanged from R9.

#define SCAN_NB 256

typedef _Float16 half8 __attribute__((ext_vector_type(8)));
typedef float f32x4 __attribute__((ext_vector_type(4)));

// ---------- CSR build ----------
__global__ __launch_bounds__(256)
void count_rank_kernel(const int* __restrict__ dst, int* __restrict__ deg,
                       int* __restrict__ rank, int e) {
    for (int i = blockIdx.x * 256 + threadIdx.x; i < e; i += gridDim.x * 256)
        rank[i] = atomicAdd(deg + dst[i], 1);
}

__global__ __launch_bounds__(256)
void blocksum_kernel(const int* __restrict__ deg, int* __restrict__ bsum, int n) {
    __shared__ int ls[256];
    const int chunk = (n + gridDim.x - 1) / gridDim.x;
    const int b0 = blockIdx.x * chunk;
    const int b1 = (b0 + chunk < n) ? b0 + chunk : n;
    int s = 0;
    for (int i = b0 + threadIdx.x; i < b1; i += 256) s += deg[i];
    ls[threadIdx.x] = s;
    __syncthreads();
    for (int off = 128; off > 0; off >>= 1) {
        if (threadIdx.x < off) ls[threadIdx.x] += ls[threadIdx.x + off];
        __syncthreads();
    }
    if (threadIdx.x == 0) bsum[blockIdx.x] = ls[0];
}

__global__ __launch_bounds__(256)
void scanb_kernel(const int* __restrict__ bsum, int* __restrict__ boff,
                  int* __restrict__ total, int nb) {
    __shared__ int ls[256];
    const int t = threadIdx.x;
    int v = (t < nb) ? bsum[t] : 0;
    ls[t] = v;
    __syncthreads();
    for (int off = 1; off < 256; off <<= 1) {
        int u = (t >= off) ? ls[t - off] : 0;
        __syncthreads();
        ls[t] += u;
        __syncthreads();
    }
    if (t < nb) boff[t] = ls[t] - v;
    if (t == 255) *total = ls[255];
}

__global__ __launch_bounds__(256)
void writeptr_kernel(const int* __restrict__ deg, const int* __restrict__ boff,
                     int* __restrict__ rowptr, int n) {
    __shared__ int ls[256];
    const int chunk = (n + gridDim.x - 1) / gridDim.x;
    const int b0 = blockIdx.x * chunk;
    const int b1 = (b0 + chunk < n) ? b0 + chunk : n;
    const int tchunk = (chunk + 255) / 256;
    const int t0 = b0 + threadIdx.x * tchunk;
    const int t1 = (t0 + tchunk < b1) ? t0 + tchunk : b1;
    int s = 0;
    for (int i = t0; i < t1; ++i) s += deg[i];
    ls[threadIdx.x] = s;
    __syncthreads();
    for (int off = 1; off < 256; off <<= 1) {
        int u = (threadIdx.x >= off) ? ls[threadIdx.x - off] : 0;
        __syncthreads();
        ls[threadIdx.x] += u;
        __syncthreads();
    }
    int run = boff[blockIdx.x] + ls[threadIdx.x] - s;
    for (int i = t0; i < t1; ++i) { rowptr[i] = run; run += deg[i]; }
}

__global__ __launch_bounds__(256)
void fill_pack_kernel(const int* __restrict__ src, const int* __restrict__ dst,
                      const float* __restrict__ eattr,
                      const int* __restrict__ rowptr, const int* __restrict__ rank,
                      int2* __restrict__ ecsr, int e) {
    for (int i = blockIdx.x * 256 + threadIdx.x; i < e; i += gridDim.x * 256) {
        int p = rowptr[dst[i]] + rank[i];
        ecsr[p] = make_int2(src[i], __float_as_int(eattr[i]));
    }
}

// ---------- linear4 via MFMA: q | s (fp32) + kv (__half2) ----------
template<int FIN, int C>
__global__ __launch_bounds__(256, 2)
void linear4_mfma_kernel(const float* __restrict__ X,
                         const float* __restrict__ Wq, const float* __restrict__ bq,
                         const float* __restrict__ Wk, const float* __restrict__ bk,
                         const float* __restrict__ Wv, const float* __restrict__ bv,
                         const float* __restrict__ Ws, const float* __restrict__ bs,
                         float* __restrict__ q, __half2* __restrict__ kv,
                         float* __restrict__ s, int n)
{
    constexpr int FOURC = 4 * C;
    constexpr int P  = FIN + 16;
    constexpr int KT = FIN / 32;
    constexpr int NT = FOURC / 16;
    __shared__ _Float16 wsh[FOURC * P] __attribute__((aligned(16)));
    __shared__ float bsh[FOURC];

    for (int i = threadIdx.x; i < FOURC * FIN; i += 256) {
        int col = i / FIN, f = i - (i / FIN) * FIN;
        float w;
        if (col < C)          w = Wq[f * C + col];
        else if (col < 2 * C) w = Ws[f * C + col - C];
        else if (col < 3 * C) w = Wk[f * C + col - 2 * C];
        else                  w = Wv[f * C + col - 3 * C];
        wsh[col * P + f] = (_Float16)w;
    }
    for (int i = threadIdx.x; i < FOURC; i += 256) {
        bsh[i] = (i < C) ? bq[i] : (i < 2 * C) ? bs[i - C]
               : (i < 3 * C) ? bk[i - 2 * C] : bv[i - 3 * C];
    }
    __syncthreads();

    const int lane = threadIdx.x & 63;
    const int wid  = threadIdx.x >> 6;
    const int m = lane & 15, g = lane >> 4;

    half8 bfrag[KT][NT];
    #pragma unroll
    for (int kt = 0; kt < KT; ++kt)
        #pragma unroll
        for (int nt = 0; nt < NT; ++nt)
            bfrag[kt][nt] = *reinterpret_cast<const half8*>(
                &wsh[(nt * 16 + m) * P + kt * 32 + g * 8]);

    const int tiles = n >> 4;   // N divisible by 16
    for (int t = blockIdx.x * 4 + wid; t < tiles; t += gridDim.x * 4) {
        const int row0 = t * 16;
        const float* xr = X + (size_t)(row0 + m) * FIN + g * 8;
        half8 afrag[KT];
        #pragma unroll
        for (int kt = 0; kt < KT; ++kt) {
            float4 u = *reinterpret_cast<const float4*>(xr + kt * 32);
            float4 w = *reinterpret_cast<const float4*>(xr + kt * 32 + 4);
            afrag[kt] = half8{(_Float16)u.x, (_Float16)u.y, (_Float16)u.z, (_Float16)u.w,
                              (_Float16)w.x, (_Float16)w.y, (_Float16)w.z, (_Float16)w.w};
        }
        #pragma unroll
        for (int nt = 0; nt < 2 * C / 16; ++nt) {
            f32x4 acc = {0.f, 0.f, 0.f, 0.f};
            #pragma unroll
            for (int kt = 0; kt < KT; ++kt)
                acc = __builtin_amdgcn_mfma_f32_16x16x32_f16(afrag[kt], bfrag[kt][nt], acc, 0, 0, 0);
            const int col = nt * 16 + m;
            const float bias = bsh[col];
            float* outp = (nt < C / 16) ? q : s;
            const int cc = (nt < C / 16) ? col : col - C;
            #pragma unroll
            for (int r = 0; r < 4; ++r)
                outp[(size_t)(row0 + g * 4 + r) * C + cc] = acc[r] + bias;
        }
        #pragma unroll
        for (int t2 = 0; t2 < C / 16; ++t2) {
            const int ntK = 2 * C / 16 + t2, ntV = 3 * C / 16 + t2;
            f32x4 aK = {0.f, 0.f, 0.f, 0.f}, aV = {0.f, 0.f, 0.f, 0.f};
            #pragma unroll
            for (int kt = 0; kt < KT; ++kt) {
                aK = __builtin_amdgcn_mfma_f32_16x16x32_f16(afrag[kt], bfrag[kt][ntK], aK, 0, 0, 0);
                aV = __builtin_amdgcn_mfma_f32_16x16x32_f16(afrag[kt], bfrag[kt][ntV], aV, 0, 0, 0);
            }
            const int ck = t2 * 16 + m;
            const float bK = bsh[2 * C + ck], bV = bsh[3 * C + ck];
            #pragma unroll
            for (int r = 0; r < 4; ++r)
                kv[(size_t)(row0 + g * 4 + r) * C + ck] = __floats2half2_rn(aK[r] + bK, aV[r] + bV);
        }
    }
}

// ---------- fc1 via MFMA: fp32 out + ELU ----------
template<int FIN, int COUT>
__global__ __launch_bounds__(256, 2)
void linear_mfma_kernel(const float* __restrict__ X, const float* __restrict__ W,
                        const float* __restrict__ b, float* __restrict__ out, int n)
{
    constexpr int P  = FIN + 16;
    constexpr int KT = FIN / 32;
    constexpr int NT = COUT / 16;
    __shared__ _Float16 wsh[COUT * P] __attribute__((aligned(16)));
    __shared__ float bsh[COUT];
    for (int i = threadIdx.x; i < COUT * FIN; i += 256) {
        int col = i / FIN, f = i - (i / FIN) * FIN;
        wsh[col * P + f] = (_Float16)W[f * COUT + col];
    }
    for (int i = threadIdx.x; i < COUT; i += 256) bsh[i] = b[i];
    __syncthreads();

    const int lane = threadIdx.x & 63;
    const int wid  = threadIdx.x >> 6;
    const int m = lane & 15, g = lane >> 4;

    half8 bfrag[KT][NT];
    #pragma unroll
    for (int kt = 0; kt < KT; ++kt)
        #pragma unroll
        for (int nt = 0; nt < NT; ++nt)
            bfrag[kt][nt] = *reinterpret_cast<const half8*>(
                &wsh[(nt * 16 + m) * P + kt * 32 + g * 8]);

    const int tiles = n >> 4;
    for (int t = blockIdx.x * 4 + wid; t < tiles; t += gridDim.x * 4) {
        const int row0 = t * 16;
        const float* xr = X + (size_t)(row0 + m) * FIN + g * 8;
        half8 afrag[KT];
        #pragma unroll
        for (int kt = 0; kt < KT; ++kt) {
            float4 u = *reinterpret_cast<const float4*>(xr + kt * 32);
            float4 w = *reinterpret_cast<const float4*>(xr + kt * 32 + 4);
            afrag[kt] = half8{(_Float16)u.x, (_Float16)u.y, (_Float16)u.z, (_Float16)u.w,
                              (_Float16)w.x, (_Float16)w.y, (_Float16)w.z, (_Float16)w.w};
        }
        #pragma unroll
        for (int nt = 0; nt < NT; ++nt) {
            f32x4 acc = {0.f, 0.f, 0.f, 0.f};
            #pragma unroll
            for (int kt = 0; kt < KT; ++kt)
                acc = __builtin_amdgcn_mfma_f32_16x16x32_f16(afrag[kt], bfrag[kt][nt], acc, 0, 0, 0);
            const int col = nt * 16 + m;
            const float bias = bsh[col];
            #pragma unroll
            for (int r = 0; r < 4; ++r) {
                float hv = acc[r] + bias;
                hv = (hv > 0.f) ? hv : expm1f(hv);
                out[(size_t)(row0 + g * 4 + r) * COUT + col] = hv;
            }
        }
    }
}

// ---------- fused conv: 2 channels/lane, no-max softmax + skip + ELU ----------
template<int C>
__global__ __launch_bounds__(256)
void conv_fused_kernel(const int* __restrict__ rowptr, const int2* __restrict__ ecsr,
                       const float* __restrict__ q, const __half2* __restrict__ kv,
                       const float* __restrict__ sres,
                       const float* __restrict__ We, const float* __restrict__ be,
                       float* __restrict__ h, float scale, int n)
{
    constexpr int LPE    = C / 2;             // lanes per edge
    constexpr int EPI    = 64 / LPE;          // edges in flight per wave (2 or 4)
    constexpr int LOG    = (C == 64) ? 5 : 4; // log2(LPE)
    constexpr int UNROLL = 4;
    const int wave = threadIdx.x >> 6;
    const int lane = threadIdx.x & 63;
    const int l    = lane & (LPE - 1);
    const int slot = lane >> LOG;
    const int c0   = 2 * l;
    const int node = blockIdx.x * 4 + wave;
    if (node >= n) return;

    const float2 wec = *reinterpret_cast<const float2*>(We + c0);
    const float2 bec = *reinterpret_cast<const float2*>(be + c0);
    const float2 qp  = *reinterpret_cast<const float2*>(q + (size_t)node * C + c0);
    const int r0 = rowptr[node], r1 = rowptr[node + 1];

    float ssum = 0.f, acc0 = 0.f, acc1 = 0.f;
    int j = r0 + slot;
    for (; j + (UNROLL - 1) * EPI < r1; j += UNROLL * EPI) {
        int2 epk[UNROLL]; float2 kvr[UNROLL];
        #pragma unroll
        for (int u = 0; u < UNROLL; ++u) epk[u] = ecsr[j + u * EPI];
        #pragma unroll
        for (int u = 0; u < UNROLL; ++u)
            kvr[u] = *reinterpret_cast<const float2*>(kv + (size_t)epk[u].x * C + c0);
        #pragma unroll
        for (int u = 0; u < UNROLL; ++u) {
            float ea = __int_as_float(epk[u].y);
            float e0 = fmaf(ea, wec.x, bec.x);
            float e1 = fmaf(ea, wec.y, bec.y);
            float2 f0 = __half22float2(*reinterpret_cast<__half2*>(&kvr[u].x)); // k0,v0
            float2 f1 = __half22float2(*reinterpret_cast<__half2*>(&kvr[u].y)); // k1,v1
            float p = fmaf(qp.x, f0.x + e0, qp.y * (f1.x + e1));
            #pragma unroll
            for (int off = LPE >> 1; off > 0; off >>= 1) p += __shfl_xor(p, off);
            float w = __expf(p * scale);
            ssum += w;
            acc0 = fmaf(w, f0.y + e0, acc0);
            acc1 = fmaf(w, f1.y + e1, acc1);
        }
    }
    for (; j < r1; j += EPI) {
        int2 epk = ecsr[j];
        float2 kvr = *reinterpret_cast<const float2*>(kv + (size_t)epk.x * C + c0);
        float ea = __int_as_float(epk.y);
        float e0 = fmaf(ea, wec.x, bec.x);
        float e1 = fmaf(ea, wec.y, bec.y);
        float2 f0 = __half22float2(*reinterpret_cast<__half2*>(&kvr.x));
        float2 f1 = __half22float2(*reinterpret_cast<__half2*>(&kvr.y));
        float p = fmaf(qp.x, f0.x + e0, qp.y * (f1.x + e1));
        #pragma unroll
        for (int off = LPE >> 1; off > 0; off >>= 1) p += __shfl_xor(p, off);
        float w = __expf(p * scale);
        ssum += w;
        acc0 = fmaf(w, f0.y + e0, acc0);
        acc1 = fmaf(w, f1.y + e1, acc1);
    }

    // merge the EPI slot streams (plain sums — no max)
    #pragma unroll
    for (int off = LPE; off < 64; off <<= 1) {
        ssum += __shfl_xor(ssum, off);
        acc0 += __shfl_xor(acc0, off);
        acc1 += __shfl_xor(acc1, off);
    }

    if (slot == 0) {
        float inv = 1.f / (ssum + 1e-16f);
        float2 sr = *reinterpret_cast<const float2*>(sres + (size_t)node * C + c0);
        float h0 = fmaf(acc0, inv, sr.x);
        float h1 = fmaf(acc1, inv, sr.y);
        h0 = (h0 > 0.f) ? h0 : expm1f(h0);
        h1 = (h1 > 0.f) ? h1 : expm1f(h1);
        *reinterpret_cast<float2*>(h + (size_t)node * C + c0) = make_float2(h0, h1);
    }
}

// ---------- fc2 + log_softmax ----------
#define H1_DIM 128
#define NC_DIM 10
__global__ __launch_bounds__(256)
void head_kernel(const float* __restrict__ Hf, const float* __restrict__ W,
                 const float* __restrict__ b, float* __restrict__ out, int n)
{
    __shared__ float wsh[H1_DIM * NC_DIM];
    __shared__ float bsh[NC_DIM];
    for (int i = threadIdx.x; i < H1_DIM * NC_DIM; i += 256) wsh[i] = W[i];
    for (int i = threadIdx.x; i < NC_DIM; i += 256) bsh[i] = b[i];
    __syncthreads();
    for (int row = blockIdx.x * 256 + threadIdx.x; row < n; row += gridDim.x * 256) {
        const float* hr = Hf + (size_t)row * H1_DIM;
        float logit[NC_DIM];
        #pragma unroll
        for (int c = 0; c < NC_DIM; ++c) logit[c] = bsh[c];
        for (int f = 0; f < H1_DIM; ++f) {
            float xv = hr[f];
            #pragma unroll
            for (int c = 0; c < NC_DIM; ++c) logit[c] = fmaf(xv, wsh[f * NC_DIM + c], logit[c]);
        }
        float m = logit[0];
        #pragma unroll
        for (int c = 1; c < NC_DIM; ++c) m = fmaxf(m, logit[c]);
        float sum = 0.f;
        #pragma unroll
        for (int c = 0; c < NC_DIM; ++c) sum += __expf(logit[c] - m);
        float lse = m + logf(sum);
        #pragma unroll
        for (int c = 0; c < NC_DIM; ++c) out[(size_t)row * NC_DIM + c] = logit[c] - lse;
    }
}

extern "C" void kernel_launch(void* const* d_in, const int* in_sizes, int n_in,
                              void* d_out, int out_size, void* d_ws, size_t ws_size,
                              hipStream_t stream) {
    const float* x   = (const float*)d_in[0];
    const int*   ei  = (const int*)d_in[1];
    const float* ea  = (const float*)d_in[2];
    const float *Wq1 = (const float*)d_in[3],  *bq1 = (const float*)d_in[4];
    const float *Wk1 = (const float*)d_in[5],  *bk1 = (const float*)d_in[6];
    const float *Wv1 = (const float*)d_in[7],  *bv1 = (const float*)d_in[8];
    const float *We1 = (const float*)d_in[9],  *be1 = (const float*)d_in[10];
    const float *Ws1 = (const float*)d_in[11], *bs1 = (const float*)d_in[12];
    const float *Wq2 = (const float*)d_in[13], *bq2 = (const float*)d_in[14];
    const float *Wk2 = (const float*)d_in[15], *bk2 = (const float*)d_in[16];
    const float *Wv2 = (const float*)d_in[17], *bv2 = (const float*)d_in[18];
    const float *We2 = (const float*)d_in[19], *be2 = (const float*)d_in[20];
    const float *Ws2 = (const float*)d_in[21], *bs2 = (const float*)d_in[22];
    const float *Wf1 = (const float*)d_in[23], *bf1 = (const float*)d_in[24];
    const float *Wf2 = (const float*)d_in[25], *bf2 = (const float*)d_in[26];

    const int N = in_sizes[0] / 64;   // 100000
    const int E = in_sizes[2];        // 1600000
    const int* src = ei;              // edge_index[0]
    const int* dst = ei + E;          // edge_index[1]

    float* wsf = (float*)d_ws;
    const size_t N64 = (size_t)N * 64;
    float* q      = wsf;                      // N*64
    __half2* kv   = (__half2*)(q + N64);      // N*64 half2 (k,v packed)
    float* s      = (float*)(kv + N64);       // N*64 (skip proj)
    float* h1     = s + N64;                  // N*32
    float* h2     = h1 + (size_t)N * 32;      // N*64
    int* deg      = (int*)(h2 + N64);         // N
    int* rowptr   = deg + N;                  // N+1
    int* bsum     = rowptr + N + 1;           // SCAN_NB
    int* boff     = bsum + SCAN_NB;           // SCAN_NB
    int* rank     = boff + SCAN_NB;           // E
    int2* ecsr    = (int2*)(rank + E);        // E (packed {src, eattr})
    float* hfc    = wsf;                      // N*128 (reuses dead q after conv2)

    float* out = (float*)d_out;

    // ---- CSR build ----
    hipMemsetAsync(deg, 0, (size_t)N * 4, stream);
    count_rank_kernel<<<2048, 256, 0, stream>>>(dst, deg, rank, E);
    blocksum_kernel<<<SCAN_NB, 256, 0, stream>>>(deg, bsum, N);
    scanb_kernel<<<1, 256, 0, stream>>>(bsum, boff, rowptr + N, SCAN_NB);
    writeptr_kernel<<<SCAN_NB, 256, 0, stream>>>(deg, boff, rowptr, N);
    fill_pack_kernel<<<4096, 256, 0, stream>>>(src, dst, ea, rowptr, rank, ecsr, E);

    const int convGrid = (N + 3) / 4;

    // ---- layer 1 (C=32) ----
    linear4_mfma_kernel<64, 32><<<1024, 256, 0, stream>>>(
        x, Wq1, bq1, Wk1, bk1, Wv1, bv1, Ws1, bs1, q, kv, s, N);
    conv_fused_kernel<32><<<convGrid, 256, 0, stream>>>(
        rowptr, ecsr, q, kv, s, We1, be1, h1, 0.17677669529663687f, N);

    // ---- layer 2 (C=64) ----
    linear4_mfma_kernel<32, 64><<<1024, 256, 0, stream>>>(
        h1, Wq2, bq2, Wk2, bk2, Wv2, bv2, Ws2, bs2, q, kv, s, N);
    conv_fused_kernel<64><<<convGrid, 256, 0, stream>>>(
        rowptr, ecsr, q, kv, s, We2, be2, h2, 0.125f, N);

    // ---- MLP head ----
    linear_mfma_kernel<64, 128><<<1024, 256, 0, stream>>>(h2, Wf1, bf1, hfc, N);
    head_kernel<<<512, 256, 0, stream>>>(hfc, Wf2, bf2, out, N);
}